// Round 7
// baseline (90.728 us; speedup 1.0000x reference)
//
#include <hip/hip_runtime.h>

// Problem constants (from reference setup_inputs): N=131072, D=512, C=1024.
constexpr int D      = 512;   // row dimension
constexpr int C      = 1024;  // num classes
constexpr int CAP    = 256;   // fixed bucket capacity per class (mean 128, ~11 sigma headroom)
constexpr int CHUNKS = 4;     // blocks per class in the gather pass

// clang native vector type (HIP's float4 is a struct; nontemporal builtin
// requires a real vector type).
typedef float f32x4 __attribute__((ext_vector_type(4)));

// ---------------------------------------------------------------------------
// DPP wave64 sum: butterfly xor1/2/4/8 via quad_perm / row mirrors (VALU pipe,
// ~4cy/stage vs ~50cy ds_bpermute), then row_bcast15/31 to fold the four
// 16-lane row sums; total lands in lane 63 -> readlane broadcast.
// ---------------------------------------------------------------------------
#define DPP_STEP(v, CTRL)                                                      \
    do {                                                                       \
        int _s = __builtin_amdgcn_update_dpp(0, __float_as_int(v), (CTRL),     \
                                             0xF, 0xF, true);                  \
        (v) += __int_as_float(_s);                                             \
    } while (0)

__device__ __forceinline__ float wave_sum_dpp(float v)
{
    DPP_STEP(v, 0xB1);   // quad_perm [1,0,3,2]  : xor 1
    DPP_STEP(v, 0x4E);   // quad_perm [2,3,0,1]  : xor 2
    DPP_STEP(v, 0x141);  // row_half_mirror      : xor 4
    DPP_STEP(v, 0x140);  // row_mirror           : xor 8
    DPP_STEP(v, 0x142);  // row_bcast15          : fold row pairs
    DPP_STEP(v, 0x143);  // row_bcast31          : fold half pairs -> lane 63
    return __int_as_float(__builtin_amdgcn_readlane(__float_as_int(v), 63));
}

// ---------------------------------------------------------------------------
// Kernel 1: scatter row indices into fixed-capacity per-class buckets.
// cursor[c] ends up as the class count.
// ---------------------------------------------------------------------------
__global__ __launch_bounds__(256) void scatter_kernel(
    const int* __restrict__ labels, int* __restrict__ cursor,
    int* __restrict__ bucket, int N)
{
    const int i = blockIdx.x * 256 + threadIdx.x;
    if (i < N) {
        const int l   = labels[i];
        const int pos = atomicAdd(&cursor[l], 1);
        bucket[l * CAP + pos] = i;
    }
}

// ---------------------------------------------------------------------------
// Kernel 2: per-class gather, 4 blocks per class. ONE WAVE PER ROW (lane
// holds 8 floats as 2x f32x4), dual-row unroll. Cross-lane reductions via
// DPP (VALU pipe) -- no DS ops in the main loop. Row loads are nontemporal
// (no reuse; keeps L2 for bucket/labels).
//   inv = rsqrt(||x||^2)
//   logZ += log(sum(exp(x*inv)))   (|x*inv|<=1 so no max pass)
//   acc[k] += x[k]*inv
// Epilogue combines the block's 4 waves in LDS, writes 512-dim partial + logZ.
// ---------------------------------------------------------------------------
__global__ __launch_bounds__(256, 6) void class_partial_kernel(
    const float* __restrict__ logits, const int* __restrict__ cursor,
    const int* __restrict__ bucket, float* __restrict__ part,
    float* __restrict__ lzpart)
{
    const int blk  = blockIdx.x;          // 0 .. C*CHUNKS-1
    const int c    = blk >> 2;
    const int ch   = blk & 3;
    const int t    = threadIdx.x;
    const int wave = t >> 6;
    const int lane = t & 63;
    const int cnt  = cursor[c];
    const int w16  = ch * 4 + wave;       // 0..15 across the class's four blocks
    const int* __restrict__ myb = bucket + c * CAP;

    float acc[8] = {0.f, 0.f, 0.f, 0.f, 0.f, 0.f, 0.f, 0.f};
    float logZ   = 0.f;

    int j = w16;
    // dual-row unroll: rows j and j+16 both valid (two independent chains)
    for (; j + 16 < cnt; j += 32) {
        const int row0 = myb[j];
        const int row1 = myb[j + 16];
        const f32x4* p0 = (const f32x4*)(logits + (size_t)row0 * D);
        const f32x4* p1 = (const f32x4*)(logits + (size_t)row1 * D);
        f32x4 a0 = __builtin_nontemporal_load(p0 + lane);
        f32x4 b0 = __builtin_nontemporal_load(p0 + lane + 64);
        f32x4 a1 = __builtin_nontemporal_load(p1 + lane);
        f32x4 b1 = __builtin_nontemporal_load(p1 + lane + 64);
        float x0[8] = {a0.x, a0.y, a0.z, a0.w, b0.x, b0.y, b0.z, b0.w};
        float x1[8] = {a1.x, a1.y, a1.z, a1.w, b1.x, b1.y, b1.z, b1.w};

        float ss0 = 0.f, ss1 = 0.f;
#pragma unroll
        for (int k = 0; k < 8; ++k) { ss0 += x0[k] * x0[k]; ss1 += x1[k] * x1[k]; }
        const float inv0 = rsqrtf(wave_sum_dpp(ss0));
        const float inv1 = rsqrtf(wave_sum_dpp(ss1));

        float e0 = 0.f, e1 = 0.f;
#pragma unroll
        for (int k = 0; k < 8; ++k) {
            e0 += __expf(x0[k] * inv0);
            e1 += __expf(x1[k] * inv1);
        }
        logZ += __logf(wave_sum_dpp(e0)) + __logf(wave_sum_dpp(e1));

#pragma unroll
        for (int k = 0; k < 8; ++k) acc[k] += x0[k] * inv0 + x1[k] * inv1;
    }
    // remainder: single rows
    for (; j < cnt; j += 16) {
        const int row0 = myb[j];
        const f32x4* p0 = (const f32x4*)(logits + (size_t)row0 * D);
        f32x4 a0 = __builtin_nontemporal_load(p0 + lane);
        f32x4 b0 = __builtin_nontemporal_load(p0 + lane + 64);
        float x0[8] = {a0.x, a0.y, a0.z, a0.w, b0.x, b0.y, b0.z, b0.w};

        float ss0 = 0.f;
#pragma unroll
        for (int k = 0; k < 8; ++k) ss0 += x0[k] * x0[k];
        const float inv0 = rsqrtf(wave_sum_dpp(ss0));

        float e0 = 0.f;
#pragma unroll
        for (int k = 0; k < 8; ++k) e0 += __expf(x0[k] * inv0);
        logZ += __logf(wave_sum_dpp(e0));

#pragma unroll
        for (int k = 0; k < 8; ++k) acc[k] += x0[k] * inv0;
    }

    // ---- epilogue: combine this block's 4 waves, write partial ----
    __shared__ float lacc[4][D];   // 8 KB
    __shared__ float lzs[4];

    ((float4*)lacc[wave])[lane]      = make_float4(acc[0], acc[1], acc[2], acc[3]);
    ((float4*)lacc[wave])[lane + 64] = make_float4(acc[4], acc[5], acc[6], acc[7]);
    if (lane == 0) lzs[wave] = logZ;
    __syncthreads();

    // thread t owns dims {2t, 2t+1}
    float2 v0 = ((const float2*)lacc[0])[t];
    float2 v1 = ((const float2*)lacc[1])[t];
    float2 v2 = ((const float2*)lacc[2])[t];
    float2 v3 = ((const float2*)lacc[3])[t];
    const float ax = v0.x + v1.x + v2.x + v3.x;
    const float ay = v0.y + v1.y + v2.y + v3.y;

    ((float2*)(part + (size_t)blk * D))[t] = make_float2(ax, ay);
    if (t == 0) lzpart[blk] = lzs[0] + lzs[1] + lzs[2] + lzs[3];
}

// ---------------------------------------------------------------------------
// Kernel 3: finalize. One block per class: combine the 4 chunk partials,
// then with W = acc/||acc||: dot(W,acc)=||acc||, sum(W)=sum(acc)/||acc||,
//   loss_c = -( ||acc|| - logZsum * sum(acc)/||acc|| ) / cnt
// ---------------------------------------------------------------------------
__global__ __launch_bounds__(256) void finalize_kernel(
    const float* __restrict__ part, const float* __restrict__ lzpart,
    const int* __restrict__ cursor, float* __restrict__ out)
{
    const int c    = blockIdx.x;
    const int t    = threadIdx.x;
    const int wave = t >> 6;
    const int lane = t & 63;

    float2 a = ((const float2*)(part + (size_t)(4 * c + 0) * D))[t];
    float2 b = ((const float2*)(part + (size_t)(4 * c + 1) * D))[t];
    float2 g = ((const float2*)(part + (size_t)(4 * c + 2) * D))[t];
    float2 h = ((const float2*)(part + (size_t)(4 * c + 3) * D))[t];
    const float ax = a.x + b.x + g.x + h.x;
    const float ay = a.y + b.y + g.y + h.y;

    float ssp = ax * ax + ay * ay;
    float smp = ax + ay;
#pragma unroll
    for (int off = 32; off; off >>= 1) {
        ssp += __shfl_xor(ssp, off, 64);
        smp += __shfl_xor(smp, off, 64);
    }

    __shared__ float2 red2[4];
    if (lane == 0) red2[wave] = make_float2(ssp, smp);
    __syncthreads();

    if (t == 0) {
        const float sstot = red2[0].x + red2[1].x + red2[2].x + red2[3].x;
        const float smtot = red2[0].y + red2[1].y + red2[2].y + red2[3].y;
        const float lzsum = lzpart[4 * c] + lzpart[4 * c + 1]
                          + lzpart[4 * c + 2] + lzpart[4 * c + 3];
        const int   cnt   = cursor[c];
        float loss = 0.f;
        if (cnt > 0 && sstot > 0.f) {
            const float nrm = sqrtf(sstot);
            loss = -(nrm - lzsum * (smtot / nrm)) / (float)cnt;
        }
        out[c] = loss;
    }
}

extern "C" void kernel_launch(void* const* d_in, const int* in_sizes, int n_in,
                              void* d_out, int out_size, void* d_ws, size_t ws_size,
                              hipStream_t stream)
{
    const float* logits = (const float*)d_in[0];
    const int*   labels = (const int*)d_in[1];
    const int N = in_sizes[1];

    // Workspace layout (~9.5 MB)
    char* w = (char*)d_ws;
    int*   cursor = (int*)w;   w += C * 4;
    int*   bucket = (int*)w;   w += (size_t)C * CAP * 4;
    float* part   = (float*)w; w += (size_t)C * CHUNKS * D * 4;
    float* lzpart = (float*)w; w += C * CHUNKS * 4;

    (void)hipMemsetAsync(cursor, 0, C * 4, stream);

    scatter_kernel<<<(N + 255) / 256, 256, 0, stream>>>(labels, cursor, bucket, N);
    class_partial_kernel<<<C * CHUNKS, 256, 0, stream>>>(logits, cursor, bucket, part, lzpart);
    finalize_kernel<<<C, 256, 0, stream>>>(part, lzpart, cursor, (float*)d_out);
}

// Round 8
// 87.492 us; speedup vs baseline: 1.0370x; 1.0370x over previous
//
#include <hip/hip_runtime.h>

// Problem constants (from reference setup_inputs): N=131072, D=512, C=1024.
constexpr int D      = 512;   // row dimension
constexpr int C      = 1024;  // num classes
constexpr int CAP    = 256;   // fixed bucket capacity per class (mean 128, ~11 sigma headroom)
constexpr int CHUNKS = 4;     // blocks per class in the gather pass

// ---------------------------------------------------------------------------
// Kernel 1: scatter row indices into fixed-capacity per-class buckets.
// cursor[c] ends up as the class count.
// ---------------------------------------------------------------------------
__global__ __launch_bounds__(256) void scatter_kernel(
    const int* __restrict__ labels, int* __restrict__ cursor,
    int* __restrict__ bucket, int N)
{
    const int i = blockIdx.x * 256 + threadIdx.x;
    if (i < N) {
        const int l   = labels[i];
        const int pos = atomicAdd(&cursor[l], 1);
        bucket[l * CAP + pos] = i;
    }
}

// ---------------------------------------------------------------------------
// Kernel 2: per-class gather, 4 blocks per class. ONE WAVE PER ROW (lane
// holds 8 floats as 2x float4), EXPLICIT 2-STAGE SOFTWARE PIPELINE: the
// next iteration's bucket entries + row data are loaded BEFORE the current
// iteration's compute chain, so each wave always has ~4KB in flight across
// the ~500cy reduction chain (probe: per-wave MLP vs HBM random-gather
// ceiling). shfl_xor butterflies (known-good from the 86.3us baseline).
//   inv = rsqrt(||x||^2)
//   logZ += log(sum(exp(x*inv)))   (|x*inv|<=1 so no max pass)
//   acc[k] += x[k]*inv
// Epilogue combines the block's 4 waves in LDS, writes 512-dim partial + logZ.
// ---------------------------------------------------------------------------
__global__ __launch_bounds__(256, 8) void class_partial_kernel(
    const float* __restrict__ logits, const int* __restrict__ cursor,
    const int* __restrict__ bucket, float* __restrict__ part,
    float* __restrict__ lzpart)
{
    const int blk  = blockIdx.x;          // 0 .. C*CHUNKS-1
    const int c    = blk >> 2;
    const int ch   = blk & 3;
    const int t    = threadIdx.x;
    const int wave = t >> 6;
    const int lane = t & 63;
    const int cnt  = cursor[c];
    const int w16  = ch * 4 + wave;       // 0..15 across the class's four blocks
    const int* __restrict__ myb = bucket + c * CAP;

    float acc[8] = {0.f, 0.f, 0.f, 0.f, 0.f, 0.f, 0.f, 0.f};
    float logZ   = 0.f;

    int j = w16;

    if (j + 16 < cnt) {
        // ---- prologue: load pair 0 ----
        int r0 = myb[j];
        int r1 = myb[j + 16];
        const float4* p0 = (const float4*)(logits + (size_t)r0 * D);
        const float4* p1 = (const float4*)(logits + (size_t)r1 * D);
        float4 a0 = p0[lane], b0 = p0[lane + 64];
        float4 a1 = p1[lane], b1 = p1[lane + 64];
        j += 32;

        // ---- pipelined main loop ----
        for (; j + 16 < cnt; j += 32) {
            // issue NEXT pair's loads first
            const int n0 = myb[j];
            const int n1 = myb[j + 16];
            const float4* q0 = (const float4*)(logits + (size_t)n0 * D);
            const float4* q1 = (const float4*)(logits + (size_t)n1 * D);
            float4 na0 = q0[lane], nb0 = q0[lane + 64];
            float4 na1 = q1[lane], nb1 = q1[lane + 64];

            // compute on CURRENT pair
            float x0[8] = {a0.x, a0.y, a0.z, a0.w, b0.x, b0.y, b0.z, b0.w};
            float x1[8] = {a1.x, a1.y, a1.z, a1.w, b1.x, b1.y, b1.z, b1.w};

            float ss0 = 0.f, ss1 = 0.f;
#pragma unroll
            for (int k = 0; k < 8; ++k) { ss0 += x0[k] * x0[k]; ss1 += x1[k] * x1[k]; }
#pragma unroll
            for (int off = 32; off; off >>= 1) {
                ss0 += __shfl_xor(ss0, off, 64);
                ss1 += __shfl_xor(ss1, off, 64);
            }
            const float inv0 = rsqrtf(ss0);
            const float inv1 = rsqrtf(ss1);

            float e0 = 0.f, e1 = 0.f;
#pragma unroll
            for (int k = 0; k < 8; ++k) {
                e0 += __expf(x0[k] * inv0);
                e1 += __expf(x1[k] * inv1);
            }
#pragma unroll
            for (int off = 32; off; off >>= 1) {
                e0 += __shfl_xor(e0, off, 64);
                e1 += __shfl_xor(e1, off, 64);
            }
            logZ += __logf(e0) + __logf(e1);

#pragma unroll
            for (int k = 0; k < 8; ++k) acc[k] += x0[k] * inv0 + x1[k] * inv1;

            // rotate next -> current
            a0 = na0; b0 = nb0; a1 = na1; b1 = nb1;
        }

        // ---- drain: compute the last loaded pair ----
        {
            float x0[8] = {a0.x, a0.y, a0.z, a0.w, b0.x, b0.y, b0.z, b0.w};
            float x1[8] = {a1.x, a1.y, a1.z, a1.w, b1.x, b1.y, b1.z, b1.w};

            float ss0 = 0.f, ss1 = 0.f;
#pragma unroll
            for (int k = 0; k < 8; ++k) { ss0 += x0[k] * x0[k]; ss1 += x1[k] * x1[k]; }
#pragma unroll
            for (int off = 32; off; off >>= 1) {
                ss0 += __shfl_xor(ss0, off, 64);
                ss1 += __shfl_xor(ss1, off, 64);
            }
            const float inv0 = rsqrtf(ss0);
            const float inv1 = rsqrtf(ss1);

            float e0 = 0.f, e1 = 0.f;
#pragma unroll
            for (int k = 0; k < 8; ++k) {
                e0 += __expf(x0[k] * inv0);
                e1 += __expf(x1[k] * inv1);
            }
#pragma unroll
            for (int off = 32; off; off >>= 1) {
                e0 += __shfl_xor(e0, off, 64);
                e1 += __shfl_xor(e1, off, 64);
            }
            logZ += __logf(e0) + __logf(e1);

#pragma unroll
            for (int k = 0; k < 8; ++k) acc[k] += x0[k] * inv0 + x1[k] * inv1;
        }
    }

    // ---- remainder: single rows ----
    for (; j < cnt; j += 16) {
        const int row0 = myb[j];
        const float4* p0 = (const float4*)(logits + (size_t)row0 * D);
        float4 a0 = p0[lane], b0 = p0[lane + 64];
        float x0[8] = {a0.x, a0.y, a0.z, a0.w, b0.x, b0.y, b0.z, b0.w};

        float ss0 = 0.f;
#pragma unroll
        for (int k = 0; k < 8; ++k) ss0 += x0[k] * x0[k];
#pragma unroll
        for (int off = 32; off; off >>= 1) ss0 += __shfl_xor(ss0, off, 64);
        const float inv0 = rsqrtf(ss0);

        float e0 = 0.f;
#pragma unroll
        for (int k = 0; k < 8; ++k) e0 += __expf(x0[k] * inv0);
#pragma unroll
        for (int off = 32; off; off >>= 1) e0 += __shfl_xor(e0, off, 64);
        logZ += __logf(e0);

#pragma unroll
        for (int k = 0; k < 8; ++k) acc[k] += x0[k] * inv0;
    }

    // ---- epilogue: combine this block's 4 waves, write partial ----
    __shared__ float lacc[4][D];   // 8 KB
    __shared__ float lzs[4];

    ((float4*)lacc[wave])[lane]      = make_float4(acc[0], acc[1], acc[2], acc[3]);
    ((float4*)lacc[wave])[lane + 64] = make_float4(acc[4], acc[5], acc[6], acc[7]);
    if (lane == 0) lzs[wave] = logZ;
    __syncthreads();

    // thread t owns dims {2t, 2t+1}
    float2 v0 = ((const float2*)lacc[0])[t];
    float2 v1 = ((const float2*)lacc[1])[t];
    float2 v2 = ((const float2*)lacc[2])[t];
    float2 v3 = ((const float2*)lacc[3])[t];
    const float ax = v0.x + v1.x + v2.x + v3.x;
    const float ay = v0.y + v1.y + v2.y + v3.y;

    ((float2*)(part + (size_t)blk * D))[t] = make_float2(ax, ay);
    if (t == 0) lzpart[blk] = lzs[0] + lzs[1] + lzs[2] + lzs[3];
}

// ---------------------------------------------------------------------------
// Kernel 3: finalize. One block per class: combine the 4 chunk partials,
// then with W = acc/||acc||: dot(W,acc)=||acc||, sum(W)=sum(acc)/||acc||,
//   loss_c = -( ||acc|| - logZsum * sum(acc)/||acc|| ) / cnt
// ---------------------------------------------------------------------------
__global__ __launch_bounds__(256) void finalize_kernel(
    const float* __restrict__ part, const float* __restrict__ lzpart,
    const int* __restrict__ cursor, float* __restrict__ out)
{
    const int c    = blockIdx.x;
    const int t    = threadIdx.x;
    const int wave = t >> 6;
    const int lane = t & 63;

    float2 a = ((const float2*)(part + (size_t)(4 * c + 0) * D))[t];
    float2 b = ((const float2*)(part + (size_t)(4 * c + 1) * D))[t];
    float2 g = ((const float2*)(part + (size_t)(4 * c + 2) * D))[t];
    float2 h = ((const float2*)(part + (size_t)(4 * c + 3) * D))[t];
    const float ax = a.x + b.x + g.x + h.x;
    const float ay = a.y + b.y + g.y + h.y;

    float ssp = ax * ax + ay * ay;
    float smp = ax + ay;
#pragma unroll
    for (int off = 32; off; off >>= 1) {
        ssp += __shfl_xor(ssp, off, 64);
        smp += __shfl_xor(smp, off, 64);
    }

    __shared__ float2 red2[4];
    if (lane == 0) red2[wave] = make_float2(ssp, smp);
    __syncthreads();

    if (t == 0) {
        const float sstot = red2[0].x + red2[1].x + red2[2].x + red2[3].x;
        const float smtot = red2[0].y + red2[1].y + red2[2].y + red2[3].y;
        const float lzsum = lzpart[4 * c] + lzpart[4 * c + 1]
                          + lzpart[4 * c + 2] + lzpart[4 * c + 3];
        const int   cnt   = cursor[c];
        float loss = 0.f;
        if (cnt > 0 && sstot > 0.f) {
            const float nrm = sqrtf(sstot);
            loss = -(nrm - lzsum * (smtot / nrm)) / (float)cnt;
        }
        out[c] = loss;
    }
}

extern "C" void kernel_launch(void* const* d_in, const int* in_sizes, int n_in,
                              void* d_out, int out_size, void* d_ws, size_t ws_size,
                              hipStream_t stream)
{
    const float* logits = (const float*)d_in[0];
    const int*   labels = (const int*)d_in[1];
    const int N = in_sizes[1];

    // Workspace layout (~9.5 MB)
    char* w = (char*)d_ws;
    int*   cursor = (int*)w;   w += C * 4;
    int*   bucket = (int*)w;   w += (size_t)C * CAP * 4;
    float* part   = (float*)w; w += (size_t)C * CHUNKS * D * 4;
    float* lzpart = (float*)w; w += C * CHUNKS * 4;

    (void)hipMemsetAsync(cursor, 0, C * 4, stream);

    scatter_kernel<<<(N + 255) / 256, 256, 0, stream>>>(labels, cursor, bucket, N);
    class_partial_kernel<<<C * CHUNKS, 256, 0, stream>>>(logits, cursor, bucket, part, lzpart);
    finalize_kernel<<<C, 256, 0, stream>>>(part, lzpart, cursor, (float*)d_out);
}